// Round 1
// baseline (876.544 us; speedup 1.0000x reference)
//
#include <hip/hip_runtime.h>

#define NSLOT 8
#define BN_EPS 1e-5f

static inline int cdiv_h(int a, int b) { return (a + b - 1) / b; }

// ---------------- CSR build ----------------

__global__ __launch_bounds__(256) void k_hist(const int* __restrict__ dst, int* __restrict__ deg, int E) {
    int i = blockIdx.x * 256 + threadIdx.x;
    if (i < E) atomicAdd(&deg[dst[i]], 1);
}

__global__ __launch_bounds__(256) void k_scan1(const int* __restrict__ deg, int* __restrict__ bsum, int n) {
    __shared__ int sd[256];
    int t = threadIdx.x;
    int i = blockIdx.x * 256 + t;
    sd[t] = (i < n) ? deg[i] : 0;
    __syncthreads();
    for (int s = 128; s > 0; s >>= 1) { if (t < s) sd[t] += sd[t + s]; __syncthreads(); }
    if (t == 0) bsum[blockIdx.x] = sd[0];
}

// single block, nb <= 512 (N <= 131072 with 256-blocks)
__global__ __launch_bounds__(512) void k_scan2(int* __restrict__ bsum, int nb, int* __restrict__ rowptr, int N, int E) {
    __shared__ int sa[512], sb[512];
    int t = threadIdx.x;
    int v = (t < nb) ? bsum[t] : 0;
    sa[t] = v; __syncthreads();
    int* cur = sa; int* nxt = sb;
    for (int off = 1; off < 512; off <<= 1) {
        int val = cur[t];
        if (t >= off) val += cur[t - off];
        nxt[t] = val;
        __syncthreads();
        int* tmp = cur; cur = nxt; nxt = tmp;
    }
    if (t < nb) bsum[t] = cur[t] - v;   // exclusive
    if (t == 0) rowptr[N] = E;
}

__global__ __launch_bounds__(256) void k_scan3(const int* __restrict__ deg, const int* __restrict__ bsum,
                                               int* __restrict__ rowptr, int n) {
    __shared__ int sa[256], sb[256];
    int t = threadIdx.x;
    int i = blockIdx.x * 256 + t;
    int v = (i < n) ? deg[i] : 0;
    sa[t] = v; __syncthreads();
    int* cur = sa; int* nxt = sb;
    for (int off = 1; off < 256; off <<= 1) {
        int val = cur[t];
        if (t >= off) val += cur[t - off];
        nxt[t] = val;
        __syncthreads();
        int* tmp = cur; cur = nxt; nxt = tmp;
    }
    if (i < n) rowptr[i] = cur[t] - v + bsum[blockIdx.x];
}

__global__ __launch_bounds__(256) void k_fill(const int* __restrict__ src, const int* __restrict__ dst,
                                              const int* __restrict__ rowptr, int* __restrict__ cursor,
                                              int* __restrict__ col, int E) {
    int i = blockIdx.x * 256 + threadIdx.x;
    if (i < E) {
        int v = dst[i];
        int pos = rowptr[v] + atomicAdd(&cursor[v], 1);
        col[pos] = src[i];
    }
}

// ---------------- graph boundaries (graph_id sorted) ----------------

__global__ __launch_bounds__(256) void k_gstart(const int* __restrict__ gid, int* __restrict__ gstart, int n, int G) {
    int i = blockIdx.x * 256 + threadIdx.x;
    if (i >= n) return;
    int g = gid[i];
    int gp = (i == 0) ? -1 : gid[i - 1];
    for (int x = gp + 1; x <= g; ++x) gstart[x] = i;
    if (i == n - 1) { for (int x = g + 1; x <= G; ++x) gstart[x] = n; }
}

// ---------------- per-node transform: p = (relu(a*y+c)) @ W  (or h @ W for layer 0) ----------------

template <int AFF>
__global__ __launch_bounds__(256) void k_transform(const float* __restrict__ xin, const float* __restrict__ W,
                                                   const float* __restrict__ cA, const float* __restrict__ cC,
                                                   float* __restrict__ p, int n) {
    __shared__ float sW[32][32];
    __shared__ float sA[32], sC[32];
    int t = threadIdx.x;
    for (int i = t; i < 1024; i += 256) sW[i >> 5][i & 31] = W[i];
    if (AFF && t < 32) { sA[t] = cA[t]; sC[t] = cC[t]; }
    __syncthreads();
    int node = blockIdx.x * 256 + t;
    if (node >= n) return;
    float x[32];
    const float4* s4 = (const float4*)(xin + (size_t)node * 32);
#pragma unroll
    for (int q = 0; q < 8; q++) {
        float4 v = s4[q];
        x[4*q] = v.x; x[4*q+1] = v.y; x[4*q+2] = v.z; x[4*q+3] = v.w;
    }
    if (AFF) {
#pragma unroll
        for (int k = 0; k < 32; k++) {
            float v = sA[k] * x[k] + sC[k];
            x[k] = v > 0.f ? v : 0.f;
        }
    }
    float acc[32];
#pragma unroll
    for (int f = 0; f < 32; f++) acc[f] = 0.f;
#pragma unroll
    for (int k = 0; k < 32; k++) {
        float xv = x[k];
#pragma unroll
        for (int f = 0; f < 32; f++) acc[f] += xv * sW[k][f];
    }
    float4* d4 = (float4*)(p + (size_t)node * 32);
#pragma unroll
    for (int q = 0; q < 8; q++) d4[q] = make_float4(acc[4*q], acc[4*q+1], acc[4*q+2], acc[4*q+3]);
}

// layer 3: p3[v] = relu(a*y2+c) . w3   (scalar per node)
__global__ __launch_bounds__(256) void k_transform3(const float* __restrict__ y2, const float* __restrict__ w3,
                                                    const float* __restrict__ cA, const float* __restrict__ cC,
                                                    float* __restrict__ p3, int n) {
    __shared__ float sw[32], sA[32], sC[32];
    int t = threadIdx.x;
    if (t < 32) { sw[t] = w3[t]; sA[t] = cA[t]; sC[t] = cC[t]; }
    __syncthreads();
    int i = blockIdx.x * 256 + t;
    if (i >= n) return;
    const float4* x4 = (const float4*)(y2 + (size_t)i * 32);
    float acc = 0.f;
#pragma unroll
    for (int q = 0; q < 8; q++) {
        float4 v = x4[q];
        float vv[4] = {v.x, v.y, v.z, v.w};
#pragma unroll
        for (int r = 0; r < 4; r++) {
            int k = q * 4 + r;
            float xv = sA[k] * vv[r] + sC[k];
            xv = xv > 0.f ? xv : 0.f;
            acc += xv * sw[k];
        }
    }
    p3[i] = acc;
}

// ---------------- aggregation: y[v] = (sum_{u->v} p[u]) / max(deg,1) + bias; fused BN stats ----------------

__global__ __launch_bounds__(256) void k_aggregate(const float* __restrict__ p, const int* __restrict__ rowptr,
                                                   const int* __restrict__ col, const float* __restrict__ bias,
                                                   float* __restrict__ y, float* __restrict__ sSum,
                                                   float* __restrict__ sSq, int n) {
    int lane = threadIdx.x & 31;
    int grp = threadIdx.x >> 5;                       // 0..7
    int groupsPerGrid = gridDim.x * 8;
    float b = bias[lane];
    float lsum = 0.f, lsq = 0.f;
    for (int node = blockIdx.x * 8 + grp; node < n; node += groupsPerGrid) {
        int s0 = rowptr[node], s1 = rowptr[node + 1];
        float acc = 0.f;
        for (int j = s0; j < s1; ++j) {
            int s = col[j];                           // wave-uniform within group
            acc += p[(size_t)s * 32 + lane];          // 128B coalesced gather
        }
        int deg = s1 - s0;
        float inv = (deg > 0) ? 1.f / (float)deg : 1.f;
        float v = acc * inv + b;
        y[(size_t)node * 32 + lane] = v;
        lsum += v; lsq += v * v;
    }
    __shared__ float sS[8][32], sQ[8][32];
    sS[grp][lane] = lsum; sQ[grp][lane] = lsq;
    __syncthreads();
    if (threadIdx.x < 32) {
        float a = 0.f, q = 0.f;
#pragma unroll
        for (int g2 = 0; g2 < 8; g2++) { a += sS[g2][threadIdx.x]; q += sQ[g2][threadIdx.x]; }
        int slot = blockIdx.x & (NSLOT - 1);
        atomicAdd(&sSum[slot * 32 + threadIdx.x], a);
        atomicAdd(&sSq[slot * 32 + threadIdx.x], q);
    }
}

__global__ __launch_bounds__(256) void k_aggregate3(const float* __restrict__ p3, const int* __restrict__ rowptr,
                                                    const int* __restrict__ col, const float* __restrict__ b1,
                                                    float* __restrict__ y3, float* __restrict__ sSum,
                                                    float* __restrict__ sSq, int n) {
    int i = blockIdx.x * 256 + threadIdx.x;
    float lsum = 0.f, lsq = 0.f;
    if (i < n) {
        int s0 = rowptr[i], s1 = rowptr[i + 1];
        float acc = 0.f;
        for (int j = s0; j < s1; ++j) acc += p3[col[j]];
        float inv = (s1 > s0) ? 1.f / (float)(s1 - s0) : 1.f;
        float v = acc * inv + b1[0];
        y3[i] = v; lsum = v; lsq = v * v;
    }
    __shared__ float sS[256], sQ[256];
    int t = threadIdx.x;
    sS[t] = lsum; sQ[t] = lsq;
    __syncthreads();
    for (int s = 128; s > 0; s >>= 1) {
        if (t < s) { sS[t] += sS[t + s]; sQ[t] += sQ[t + s]; }
        __syncthreads();
    }
    if (t == 0) {
        int slot = blockIdx.x & (NSLOT - 1);
        atomicAdd(&sSum[slot * 32], sS[0]);
        atomicAdd(&sSq[slot * 32], sQ[0]);
    }
}

// ---------------- BN stat finalize -> affine coefs ----------------

__global__ void k_stats(const float* __restrict__ sSum, const float* __restrict__ sSq,
                        const float* __restrict__ g, const float* __restrict__ b,
                        float* __restrict__ cA, float* __restrict__ cC, int C, float invN) {
    int f = threadIdx.x;
    if (f < C) {
        float S = 0.f, Q = 0.f;
        for (int s = 0; s < NSLOT; s++) { S += sSum[s * 32 + f]; Q += sSq[s * 32 + f]; }
        float m = S * invN;
        float var = Q * invN - m * m;
        if (var < 0.f) var = 0.f;
        float inv = rsqrtf(var + BN_EPS);
        float a = g[f] * inv;
        cA[f] = a;
        cC[f] = b[f] - m * a;
    }
}

// ---------------- per-graph mean pool + MLP ----------------

__global__ __launch_bounds__(256) void k_pool_mlp(const float* __restrict__ h, const float* __restrict__ y0,
                                                  const float* __restrict__ y1, const float* __restrict__ y2,
                                                  const float* __restrict__ y3, const float* __restrict__ cA,
                                                  const float* __restrict__ cC, const int* __restrict__ gstart,
                                                  const float* __restrict__ w0, const float* __restrict__ b0,
                                                  const float* __restrict__ w1, const float* __restrict__ b1,
                                                  const float* __restrict__ w2, const float* __restrict__ b2,
                                                  float* __restrict__ out) {
    int g = blockIdx.x;
    int t = threadIdx.x;
    int s0 = gstart[g], s1 = gstart[g + 1];
    __shared__ float hg[129];
    __shared__ float hid1[128];
    __shared__ float hid2[64];
    if (t < 129) {
        float acc = 0.f;
        if (t < 32) {
            for (int n = s0; n < s1; ++n) acc += h[(size_t)n * 32 + t];
        } else if (t < 64) {
            int c = t - 32; float a = cA[c], cc = cC[c];
            for (int n = s0; n < s1; ++n) { float v = a * y0[(size_t)n * 32 + c] + cc; acc += v > 0.f ? v : 0.f; }
        } else if (t < 96) {
            int c = t - 64; float a = cA[32 + c], cc = cC[32 + c];
            for (int n = s0; n < s1; ++n) { float v = a * y1[(size_t)n * 32 + c] + cc; acc += v > 0.f ? v : 0.f; }
        } else if (t < 128) {
            int c = t - 96; float a = cA[64 + c], cc = cC[64 + c];
            for (int n = s0; n < s1; ++n) { float v = a * y2[(size_t)n * 32 + c] + cc; acc += v > 0.f ? v : 0.f; }
        } else {
            float a = cA[96], cc = cC[96];
            for (int n = s0; n < s1; ++n) { float v = a * y3[n] + cc; acc += v > 0.f ? v : 0.f; }
        }
        float inv = (s1 > s0) ? 1.f / (float)(s1 - s0) : 1.f;
        hg[t] = acc * inv;
    }
    __syncthreads();
    if (t < 128) {
        float a = b0[t];
        for (int i = 0; i < 129; i++) a += hg[i] * w0[i * 128 + t];
        hid1[t] = a > 0.f ? a : 0.f;
    }
    __syncthreads();
    if (t < 64) {
        float a = b1[t];
        for (int i = 0; i < 128; i++) a += hid1[i] * w1[i * 64 + t];
        hid2[t] = a > 0.f ? a : 0.f;
    }
    __syncthreads();
    if (t < 64) {
        float v = hid2[t] * w2[t];
        for (int off = 32; off > 0; off >>= 1) v += __shfl_down(v, off, 64);
        if (t == 0) out[g] = v + b2[0];
    }
}

// ---------------- launcher ----------------

extern "C" void kernel_launch(void* const* d_in, const int* in_sizes, int n_in,
                              void* d_out, int out_size, void* d_ws, size_t ws_size,
                              hipStream_t stream) {
    const float* h   = (const float*)d_in[0];
    const int* src   = (const int*)d_in[1];
    const int* dst   = (const int*)d_in[2];
    const int* gid   = (const int*)d_in[3];
    const float* convw[4], *convb[4], *bng[4], *bnb[4];
    for (int i = 0; i < 4; i++) {
        convw[i] = (const float*)d_in[4 + 4 * i];
        convb[i] = (const float*)d_in[5 + 4 * i];
        bng[i]   = (const float*)d_in[6 + 4 * i];
        bnb[i]   = (const float*)d_in[7 + 4 * i];
    }
    const float* mw0 = (const float*)d_in[20];
    const float* mb0 = (const float*)d_in[21];
    const float* mw1 = (const float*)d_in[22];
    const float* mb1 = (const float*)d_in[23];
    const float* mw2 = (const float*)d_in[24];
    const float* mb2 = (const float*)d_in[25];

    const int N = in_sizes[0] / 32;
    const int E = in_sizes[1];
    const int G = out_size;

    // workspace bump allocator (512B aligned)
    char* ws = (char*)d_ws;
    size_t off = 0;
    auto alloc = [&](size_t bytes) -> void* {
        void* p = ws + off;
        off += (bytes + 511) & ~(size_t)511;
        return p;
    };
    int* deg    = (int*)alloc((size_t)N * 4);
    int* rowptr = (int*)alloc((size_t)(N + 1) * 4);
    int* cursor = (int*)alloc((size_t)N * 4);
    int* col    = (int*)alloc((size_t)E * 4);
    int* gstart = (int*)alloc((size_t)(G + 1) * 4);
    int* bsum   = (int*)alloc((size_t)cdiv_h(N, 256) * 4);
    float* p    = (float*)alloc((size_t)N * 32 * 4);
    float* y0   = (float*)alloc((size_t)N * 32 * 4);
    float* y1   = (float*)alloc((size_t)N * 32 * 4);
    float* y2   = (float*)alloc((size_t)N * 32 * 4);
    float* y3   = (float*)alloc((size_t)N * 4);
    float* sSum = (float*)alloc((size_t)4 * NSLOT * 32 * 4);
    float* sSq  = (float*)alloc((size_t)4 * NSLOT * 32 * 4);
    float* cAa  = (float*)alloc((size_t)4 * 32 * 4);
    float* cCc  = (float*)alloc((size_t)4 * 32 * 4);
    (void)ws_size; (void)n_in;

    const int NB_E = cdiv_h(E, 256);
    const int NB_N = cdiv_h(N, 256);
    const float invN = 1.f / (float)N;

    // zero-init (ws is poisoned 0xAA before every call)
    hipMemsetAsync(deg, 0, (size_t)N * 4, stream);
    hipMemsetAsync(cursor, 0, (size_t)N * 4, stream);
    hipMemsetAsync(sSum, 0, (size_t)4 * NSLOT * 32 * 4, stream);
    hipMemsetAsync(sSq, 0, (size_t)4 * NSLOT * 32 * 4, stream);

    // CSR build (keyed by dst)
    k_hist<<<NB_E, 256, 0, stream>>>(dst, deg, E);
    k_scan1<<<NB_N, 256, 0, stream>>>(deg, bsum, N);
    k_scan2<<<1, 512, 0, stream>>>(bsum, NB_N, rowptr, N, E);
    k_scan3<<<NB_N, 256, 0, stream>>>(deg, bsum, rowptr, N);
    k_fill<<<NB_E, 256, 0, stream>>>(src, dst, rowptr, cursor, col, E);
    k_gstart<<<NB_N, 256, 0, stream>>>(gid, gstart, N, G);

    const int AGG_BLOCKS = 1024;

    // layer 0
    k_transform<0><<<NB_N, 256, 0, stream>>>(h, convw[0], nullptr, nullptr, p, N);
    k_aggregate<<<AGG_BLOCKS, 256, 0, stream>>>(p, rowptr, col, convb[0], y0, sSum + 0 * NSLOT * 32, sSq + 0 * NSLOT * 32, N);
    k_stats<<<1, 32, 0, stream>>>(sSum + 0 * NSLOT * 32, sSq + 0 * NSLOT * 32, bng[0], bnb[0], cAa + 0, cCc + 0, 32, invN);
    // layer 1
    k_transform<1><<<NB_N, 256, 0, stream>>>(y0, convw[1], cAa + 0, cCc + 0, p, N);
    k_aggregate<<<AGG_BLOCKS, 256, 0, stream>>>(p, rowptr, col, convb[1], y1, sSum + 1 * NSLOT * 32, sSq + 1 * NSLOT * 32, N);
    k_stats<<<1, 32, 0, stream>>>(sSum + 1 * NSLOT * 32, sSq + 1 * NSLOT * 32, bng[1], bnb[1], cAa + 32, cCc + 32, 32, invN);
    // layer 2
    k_transform<1><<<NB_N, 256, 0, stream>>>(y1, convw[2], cAa + 32, cCc + 32, p, N);
    k_aggregate<<<AGG_BLOCKS, 256, 0, stream>>>(p, rowptr, col, convb[2], y2, sSum + 2 * NSLOT * 32, sSq + 2 * NSLOT * 32, N);
    k_stats<<<1, 32, 0, stream>>>(sSum + 2 * NSLOT * 32, sSq + 2 * NSLOT * 32, bng[2], bnb[2], cAa + 64, cCc + 64, 32, invN);
    // layer 3 (32 -> 1, pre-multiplied so the gather is scalar)
    k_transform3<<<NB_N, 256, 0, stream>>>(y2, convw[3], cAa + 64, cCc + 64, (float*)p, N);
    k_aggregate3<<<NB_N, 256, 0, stream>>>((float*)p, rowptr, col, convb[3], y3, sSum + 3 * NSLOT * 32, sSq + 3 * NSLOT * 32, N);
    k_stats<<<1, 32, 0, stream>>>(sSum + 3 * NSLOT * 32, sSq + 3 * NSLOT * 32, bng[3], bnb[3], cAa + 96, cCc + 96, 1, invN);

    // pooling + MLP
    k_pool_mlp<<<G, 256, 0, stream>>>(h, y0, y1, y2, y3, cAa, cCc, gstart,
                                      mw0, mb0, mw1, mb1, mw2, mb2, (float*)d_out);
}

// Round 2
// 478.018 us; speedup vs baseline: 1.8337x; 1.8337x over previous
//
#include <hip/hip_runtime.h>

#define NSLOT 32
#define BN_EPS 1e-5f

static inline int cdiv_h(int a, int b) { return (a + b - 1) / b; }

__device__ __forceinline__ float4 f4add(float4 a, float4 b) {
    return make_float4(a.x + b.x, a.y + b.y, a.z + b.z, a.w + b.w);
}

// ---------------- CSR build ----------------

__global__ __launch_bounds__(256) void k_hist(const int* __restrict__ dst, int* __restrict__ deg, int E) {
    int i = blockIdx.x * 256 + threadIdx.x;
    if (i < E) atomicAdd(&deg[dst[i]], 1);
}

__global__ __launch_bounds__(256) void k_scan1(const int* __restrict__ deg, int* __restrict__ bsum, int n) {
    __shared__ int sd[256];
    int t = threadIdx.x;
    int i = blockIdx.x * 256 + t;
    sd[t] = (i < n) ? deg[i] : 0;
    __syncthreads();
    for (int s = 128; s > 0; s >>= 1) { if (t < s) sd[t] += sd[t + s]; __syncthreads(); }
    if (t == 0) bsum[blockIdx.x] = sd[0];
}

// single block, nb <= 512
__global__ __launch_bounds__(512) void k_scan2(int* __restrict__ bsum, int nb, int* __restrict__ rowptr, int N, int E) {
    __shared__ int sa[512], sb[512];
    int t = threadIdx.x;
    int v = (t < nb) ? bsum[t] : 0;
    sa[t] = v; __syncthreads();
    int* cur = sa; int* nxt = sb;
    for (int off = 1; off < 512; off <<= 1) {
        int val = cur[t];
        if (t >= off) val += cur[t - off];
        nxt[t] = val;
        __syncthreads();
        int* tmp = cur; cur = nxt; nxt = tmp;
    }
    if (t < nb) bsum[t] = cur[t] - v;   // exclusive
    if (t == 0) rowptr[N] = E;
}

__global__ __launch_bounds__(256) void k_scan3(const int* __restrict__ deg, const int* __restrict__ bsum,
                                               int* __restrict__ rowptr, int n) {
    __shared__ int sa[256], sb[256];
    int t = threadIdx.x;
    int i = blockIdx.x * 256 + t;
    int v = (i < n) ? deg[i] : 0;
    sa[t] = v; __syncthreads();
    int* cur = sa; int* nxt = sb;
    for (int off = 1; off < 256; off <<= 1) {
        int val = cur[t];
        if (t >= off) val += cur[t - off];
        nxt[t] = val;
        __syncthreads();
        int* tmp = cur; cur = nxt; nxt = tmp;
    }
    if (i < n) rowptr[i] = cur[t] - v + bsum[blockIdx.x];
}

__global__ __launch_bounds__(256) void k_fill(const int* __restrict__ src, const int* __restrict__ dst,
                                              const int* __restrict__ rowptr, int* __restrict__ cursor,
                                              int* __restrict__ col, int E) {
    int i = blockIdx.x * 256 + threadIdx.x;
    if (i < E) {
        int v = dst[i];
        int pos = rowptr[v] + atomicAdd(&cursor[v], 1);
        col[pos] = src[i];
    }
}

// ---------------- graph boundaries (graph_id sorted) ----------------

__global__ __launch_bounds__(256) void k_gstart(const int* __restrict__ gid, int* __restrict__ gstart, int n, int G) {
    int i = blockIdx.x * 256 + threadIdx.x;
    if (i >= n) return;
    int g = gid[i];
    int gp = (i == 0) ? -1 : gid[i - 1];
    for (int x = gp + 1; x <= g; ++x) gstart[x] = i;
    if (i == n - 1) { for (int x = g + 1; x <= G; ++x) gstart[x] = n; }
}

// ---------------- per-node transform: p = (relu(a*y+c)) @ W  (or h @ W for layer 0) ----------------

template <int AFF>
__global__ __launch_bounds__(256) void k_transform(const float* __restrict__ xin, const float* __restrict__ W,
                                                   const float* __restrict__ cA, const float* __restrict__ cC,
                                                   float* __restrict__ p, int n) {
    __shared__ float sW[32][32];
    __shared__ float sA[32], sC[32];
    int t = threadIdx.x;
    for (int i = t; i < 1024; i += 256) sW[i >> 5][i & 31] = W[i];
    if (AFF && t < 32) { sA[t] = cA[t]; sC[t] = cC[t]; }
    __syncthreads();
    int node = blockIdx.x * 256 + t;
    if (node >= n) return;
    float x[32];
    const float4* s4 = (const float4*)(xin + (size_t)node * 32);
#pragma unroll
    for (int q = 0; q < 8; q++) {
        float4 v = s4[q];
        x[4*q] = v.x; x[4*q+1] = v.y; x[4*q+2] = v.z; x[4*q+3] = v.w;
    }
    if (AFF) {
#pragma unroll
        for (int k = 0; k < 32; k++) {
            float v = sA[k] * x[k] + sC[k];
            x[k] = v > 0.f ? v : 0.f;
        }
    }
    float acc[32];
#pragma unroll
    for (int f = 0; f < 32; f++) acc[f] = 0.f;
#pragma unroll
    for (int k = 0; k < 32; k++) {
        float xv = x[k];
#pragma unroll
        for (int f = 0; f < 32; f++) acc[f] += xv * sW[k][f];
    }
    float4* d4 = (float4*)(p + (size_t)node * 32);
#pragma unroll
    for (int q = 0; q < 8; q++) d4[q] = make_float4(acc[4*q], acc[4*q+1], acc[4*q+2], acc[4*q+3]);
}

// layer 3: p3[v] = relu(a*y2+c) . w3   (scalar per node)
__global__ __launch_bounds__(256) void k_transform3(const float* __restrict__ y2, const float* __restrict__ w3,
                                                    const float* __restrict__ cA, const float* __restrict__ cC,
                                                    float* __restrict__ p3, int n) {
    __shared__ float sw[32], sA[32], sC[32];
    int t = threadIdx.x;
    if (t < 32) { sw[t] = w3[t]; sA[t] = cA[t]; sC[t] = cC[t]; }
    __syncthreads();
    int i = blockIdx.x * 256 + t;
    if (i >= n) return;
    const float4* x4 = (const float4*)(y2 + (size_t)i * 32);
    float acc = 0.f;
#pragma unroll
    for (int q = 0; q < 8; q++) {
        float4 v = x4[q];
        float vv[4] = {v.x, v.y, v.z, v.w};
#pragma unroll
        for (int r = 0; r < 4; r++) {
            int k = q * 4 + r;
            float xv = sA[k] * vv[r] + sC[k];
            xv = xv > 0.f ? xv : 0.f;
            acc += xv * sw[k];
        }
    }
    p3[i] = acc;
}

// ---------------- aggregation: y[v] = (sum_{u->v} p[u]) / max(deg,1) + bias; fused BN stats ----------------
// 8 lanes/node (float4 per lane), one node per group, 4-deep unrolled gather.

__global__ __launch_bounds__(256) void k_aggregate(const float4* __restrict__ p4, const int* __restrict__ rowptr,
                                                   const int* __restrict__ col, const float* __restrict__ bias,
                                                   float4* __restrict__ y4, float* __restrict__ sSum,
                                                   float* __restrict__ sSq, int n) {
    int t = threadIdx.x;
    int lane = t & 7;          // float4 slot within the 32 channels
    int grp = t >> 3;          // 0..31 : node within block
    int node = blockIdx.x * 32 + grp;
    float4 vout = make_float4(0.f, 0.f, 0.f, 0.f);
    if (node < n) {
        int s0 = rowptr[node], s1 = rowptr[node + 1];
        float4 a0 = vout, a1 = vout, a2 = vout, a3 = vout;
        int j = s0;
        for (; j + 4 <= s1; j += 4) {
            int c0 = col[j], c1 = col[j + 1], c2 = col[j + 2], c3 = col[j + 3];
            float4 g0 = p4[(size_t)c0 * 8 + lane];
            float4 g1 = p4[(size_t)c1 * 8 + lane];
            float4 g2 = p4[(size_t)c2 * 8 + lane];
            float4 g3 = p4[(size_t)c3 * 8 + lane];
            a0 = f4add(a0, g0); a1 = f4add(a1, g1); a2 = f4add(a2, g2); a3 = f4add(a3, g3);
        }
        for (; j < s1; ++j) {
            int c = col[j];
            a0 = f4add(a0, p4[(size_t)c * 8 + lane]);
        }
        float4 s = f4add(f4add(a0, a1), f4add(a2, a3));
        int deg = s1 - s0;
        float inv = (deg > 0) ? 1.f / (float)deg : 1.f;
        float4 b = ((const float4*)bias)[lane];
        vout = make_float4(s.x * inv + b.x, s.y * inv + b.y, s.z * inv + b.z, s.w * inv + b.w);
        y4[(size_t)node * 8 + lane] = vout;
    }
    // BN stats: channel = lane*4+k
    __shared__ float sS[32][32];
    __shared__ float sQ[32][32];
    ((float4*)&sS[grp][lane * 4])[0] = vout;
    ((float4*)&sQ[grp][lane * 4])[0] = make_float4(vout.x * vout.x, vout.y * vout.y,
                                                   vout.z * vout.z, vout.w * vout.w);
    __syncthreads();
    if (t < 32) {
        float S = 0.f, Q = 0.f;
#pragma unroll
        for (int g2 = 0; g2 < 32; g2++) { S += sS[g2][t]; Q += sQ[g2][t]; }
        int slot = blockIdx.x & (NSLOT - 1);
        atomicAdd(&sSum[slot * 32 + t], S);
        atomicAdd(&sSq[slot * 32 + t], Q);
    }
}

__global__ __launch_bounds__(256) void k_aggregate3(const float* __restrict__ p3, const int* __restrict__ rowptr,
                                                    const int* __restrict__ col, const float* __restrict__ b1,
                                                    float* __restrict__ y3, float* __restrict__ sSum,
                                                    float* __restrict__ sSq, int n) {
    int i = blockIdx.x * 256 + threadIdx.x;
    float lsum = 0.f, lsq = 0.f;
    if (i < n) {
        int s0 = rowptr[i], s1 = rowptr[i + 1];
        float a0 = 0.f, a1 = 0.f, a2 = 0.f, a3 = 0.f;
        int j = s0;
        for (; j + 4 <= s1; j += 4) {
            int c0 = col[j], c1 = col[j + 1], c2 = col[j + 2], c3 = col[j + 3];
            a0 += p3[c0]; a1 += p3[c1]; a2 += p3[c2]; a3 += p3[c3];
        }
        for (; j < s1; ++j) a0 += p3[col[j]];
        float acc = (a0 + a1) + (a2 + a3);
        float inv = (s1 > s0) ? 1.f / (float)(s1 - s0) : 1.f;
        float v = acc * inv + b1[0];
        y3[i] = v; lsum = v; lsq = v * v;
    }
    __shared__ float sS[256], sQ[256];
    int t = threadIdx.x;
    sS[t] = lsum; sQ[t] = lsq;
    __syncthreads();
    for (int s = 128; s > 0; s >>= 1) {
        if (t < s) { sS[t] += sS[t + s]; sQ[t] += sQ[t + s]; }
        __syncthreads();
    }
    if (t == 0) {
        int slot = blockIdx.x & (NSLOT - 1);
        atomicAdd(&sSum[slot * 32], sS[0]);
        atomicAdd(&sSq[slot * 32], sQ[0]);
    }
}

// ---------------- BN stat finalize -> affine coefs ----------------

__global__ void k_stats(const float* __restrict__ sSum, const float* __restrict__ sSq,
                        const float* __restrict__ g, const float* __restrict__ b,
                        float* __restrict__ cA, float* __restrict__ cC, int C, float invN) {
    int f = threadIdx.x;
    if (f < C) {
        float S = 0.f, Q = 0.f;
        for (int s = 0; s < NSLOT; s++) { S += sSum[s * 32 + f]; Q += sSq[s * 32 + f]; }
        float m = S * invN;
        float var = Q * invN - m * m;
        if (var < 0.f) var = 0.f;
        float inv = rsqrtf(var + BN_EPS);
        float a = g[f] * inv;
        cA[f] = a;
        cC[f] = b[f] - m * a;
    }
}

// ---------------- per-graph mean pool + MLP ----------------
// 256 threads = 8 node-slots x 32 lanes; lane -> (array, float4-chunk); coalesced float4 reads.

__global__ __launch_bounds__(256) void k_pool_mlp(const float* __restrict__ h, const float* __restrict__ y0,
                                                  const float* __restrict__ y1, const float* __restrict__ y2,
                                                  const float* __restrict__ y3, const float* __restrict__ cA,
                                                  const float* __restrict__ cC, const int* __restrict__ gstart,
                                                  const float* __restrict__ w0, const float* __restrict__ b0,
                                                  const float* __restrict__ w1, const float* __restrict__ b1,
                                                  const float* __restrict__ w2, const float* __restrict__ b2,
                                                  float* __restrict__ out) {
    int g = blockIdx.x;
    int t = threadIdx.x;
    int s0 = gstart[g], s1 = gstart[g + 1];
    int lane = t & 31, slot = t >> 5;
    int arr = lane >> 3, sub = lane & 7;
    const float* bases0 = (arr == 0) ? h : (arr == 1) ? y0 : (arr == 2) ? y1 : y2;
    const float4* bp = (const float4*)bases0;
    float4 a4 = make_float4(1.f, 1.f, 1.f, 1.f);
    float4 c4 = make_float4(0.f, 0.f, 0.f, 0.f);
    bool aff = (arr > 0);
    if (aff) {
        a4 = ((const float4*)cA)[(arr - 1) * 8 + sub];
        c4 = ((const float4*)cC)[(arr - 1) * 8 + sub];
    }
    float4 acc = make_float4(0.f, 0.f, 0.f, 0.f);
    for (int n = s0 + slot; n < s1; n += 8) {
        float4 v = bp[(size_t)n * 8 + sub];
        if (aff) {
            float vx = fmaf(a4.x, v.x, c4.x); vx = vx > 0.f ? vx : 0.f;
            float vy = fmaf(a4.y, v.y, c4.y); vy = vy > 0.f ? vy : 0.f;
            float vz = fmaf(a4.z, v.z, c4.z); vz = vz > 0.f ? vz : 0.f;
            float vw = fmaf(a4.w, v.w, c4.w); vw = vw > 0.f ? vw : 0.f;
            v = make_float4(vx, vy, vz, vw);
        }
        acc = f4add(acc, v);
    }
    __shared__ float sP[8][128];
    __shared__ float sY[8];
    ((float4*)&sP[slot][lane * 4])[0] = acc;   // hg position = lane*4+k (+32*arr folded in)
    if (t < 8) {
        float a = cA[96], c = cC[96], s = 0.f;
        for (int n = s0 + t; n < s1; n += 8) {
            float v = fmaf(a, y3[n], c);
            s += v > 0.f ? v : 0.f;
        }
        sY[t] = s;
    }
    __syncthreads();
    __shared__ float hg[129];
    __shared__ float hid1[128];
    __shared__ float hid2[64];
    float inv = (s1 > s0) ? 1.f / (float)(s1 - s0) : 1.f;
    if (t < 128) {
        float S = 0.f;
#pragma unroll
        for (int s = 0; s < 8; s++) S += sP[s][t];
        hg[t] = S * inv;
    } else if (t == 128) {
        float S = 0.f;
#pragma unroll
        for (int s = 0; s < 8; s++) S += sY[s];
        hg[128] = S * inv;
    }
    __syncthreads();
    if (t < 128) {
        float a = b0[t];
        for (int i = 0; i < 129; i++) a += hg[i] * w0[i * 128 + t];
        hid1[t] = a > 0.f ? a : 0.f;
    }
    __syncthreads();
    if (t < 64) {
        float a = b1[t];
        for (int i = 0; i < 128; i++) a += hid1[i] * w1[i * 64 + t];
        hid2[t] = a > 0.f ? a : 0.f;
    }
    __syncthreads();
    if (t < 64) {
        float v = hid2[t] * w2[t];
        for (int off = 32; off > 0; off >>= 1) v += __shfl_down(v, off, 64);
        if (t == 0) out[g] = v + b2[0];
    }
}

// ---------------- launcher ----------------

extern "C" void kernel_launch(void* const* d_in, const int* in_sizes, int n_in,
                              void* d_out, int out_size, void* d_ws, size_t ws_size,
                              hipStream_t stream) {
    const float* h   = (const float*)d_in[0];
    const int* src   = (const int*)d_in[1];
    const int* dst   = (const int*)d_in[2];
    const int* gid   = (const int*)d_in[3];
    const float* convw[4], *convb[4], *bng[4], *bnb[4];
    for (int i = 0; i < 4; i++) {
        convw[i] = (const float*)d_in[4 + 4 * i];
        convb[i] = (const float*)d_in[5 + 4 * i];
        bng[i]   = (const float*)d_in[6 + 4 * i];
        bnb[i]   = (const float*)d_in[7 + 4 * i];
    }
    const float* mw0 = (const float*)d_in[20];
    const float* mb0 = (const float*)d_in[21];
    const float* mw1 = (const float*)d_in[22];
    const float* mb1 = (const float*)d_in[23];
    const float* mw2 = (const float*)d_in[24];
    const float* mb2 = (const float*)d_in[25];

    const int N = in_sizes[0] / 32;
    const int E = in_sizes[1];
    const int G = out_size;

    // workspace bump allocator (512B aligned)
    char* ws = (char*)d_ws;
    size_t off = 0;
    auto alloc = [&](size_t bytes) -> void* {
        void* p = ws + off;
        off += (bytes + 511) & ~(size_t)511;
        return p;
    };
    int* deg    = (int*)alloc((size_t)N * 4);
    int* rowptr = (int*)alloc((size_t)(N + 1) * 4);
    int* cursor = (int*)alloc((size_t)N * 4);
    int* col    = (int*)alloc((size_t)E * 4);
    int* gstart = (int*)alloc((size_t)(G + 1) * 4);
    int* bsum   = (int*)alloc((size_t)cdiv_h(N, 256) * 4);
    float* p    = (float*)alloc((size_t)N * 32 * 4);
    float* y0   = (float*)alloc((size_t)N * 32 * 4);
    float* y1   = (float*)alloc((size_t)N * 32 * 4);
    float* y2   = (float*)alloc((size_t)N * 32 * 4);
    float* y3   = (float*)alloc((size_t)N * 4);
    float* sSum = (float*)alloc((size_t)4 * NSLOT * 32 * 4);
    float* sSq  = (float*)alloc((size_t)4 * NSLOT * 32 * 4);
    float* cAa  = (float*)alloc((size_t)4 * 32 * 4);
    float* cCc  = (float*)alloc((size_t)4 * 32 * 4);
    (void)ws_size; (void)n_in;

    const int NB_E = cdiv_h(E, 256);
    const int NB_N = cdiv_h(N, 256);
    const int NB_AG = cdiv_h(N, 32);   // one node per 8-lane group
    const float invN = 1.f / (float)N;

    // zero-init (ws is poisoned 0xAA before every call)
    hipMemsetAsync(deg, 0, (size_t)N * 4, stream);
    hipMemsetAsync(cursor, 0, (size_t)N * 4, stream);
    hipMemsetAsync(sSum, 0, (size_t)4 * NSLOT * 32 * 4, stream);
    hipMemsetAsync(sSq, 0, (size_t)4 * NSLOT * 32 * 4, stream);

    // CSR build (keyed by dst)
    k_hist<<<NB_E, 256, 0, stream>>>(dst, deg, E);
    k_scan1<<<NB_N, 256, 0, stream>>>(deg, bsum, N);
    k_scan2<<<1, 512, 0, stream>>>(bsum, NB_N, rowptr, N, E);
    k_scan3<<<NB_N, 256, 0, stream>>>(deg, bsum, rowptr, N);
    k_fill<<<NB_E, 256, 0, stream>>>(src, dst, rowptr, cursor, col, E);
    k_gstart<<<NB_N, 256, 0, stream>>>(gid, gstart, N, G);

    // layer 0
    k_transform<0><<<NB_N, 256, 0, stream>>>(h, convw[0], nullptr, nullptr, p, N);
    k_aggregate<<<NB_AG, 256, 0, stream>>>((const float4*)p, rowptr, col, convb[0], (float4*)y0,
                                           sSum + 0 * NSLOT * 32, sSq + 0 * NSLOT * 32, N);
    k_stats<<<1, 32, 0, stream>>>(sSum + 0 * NSLOT * 32, sSq + 0 * NSLOT * 32, bng[0], bnb[0], cAa + 0, cCc + 0, 32, invN);
    // layer 1
    k_transform<1><<<NB_N, 256, 0, stream>>>(y0, convw[1], cAa + 0, cCc + 0, p, N);
    k_aggregate<<<NB_AG, 256, 0, stream>>>((const float4*)p, rowptr, col, convb[1], (float4*)y1,
                                           sSum + 1 * NSLOT * 32, sSq + 1 * NSLOT * 32, N);
    k_stats<<<1, 32, 0, stream>>>(sSum + 1 * NSLOT * 32, sSq + 1 * NSLOT * 32, bng[1], bnb[1], cAa + 32, cCc + 32, 32, invN);
    // layer 2
    k_transform<1><<<NB_N, 256, 0, stream>>>(y1, convw[2], cAa + 32, cCc + 32, p, N);
    k_aggregate<<<NB_AG, 256, 0, stream>>>((const float4*)p, rowptr, col, convb[2], (float4*)y2,
                                           sSum + 2 * NSLOT * 32, sSq + 2 * NSLOT * 32, N);
    k_stats<<<1, 32, 0, stream>>>(sSum + 2 * NSLOT * 32, sSq + 2 * NSLOT * 32, bng[2], bnb[2], cAa + 64, cCc + 64, 32, invN);
    // layer 3 (32 -> 1, pre-multiplied so the gather is scalar)
    k_transform3<<<NB_N, 256, 0, stream>>>(y2, convw[3], cAa + 64, cCc + 64, (float*)p, N);
    k_aggregate3<<<NB_N, 256, 0, stream>>>((float*)p, rowptr, col, convb[3], y3,
                                           sSum + 3 * NSLOT * 32, sSq + 3 * NSLOT * 32, N);
    k_stats<<<1, 32, 0, stream>>>(sSum + 3 * NSLOT * 32, sSq + 3 * NSLOT * 32, bng[3], bnb[3], cAa + 96, cCc + 96, 1, invN);

    // pooling + MLP
    k_pool_mlp<<<G, 256, 0, stream>>>(h, y0, y1, y2, y3, cAa, cCc, gstart,
                                      mw0, mb0, mw1, mb1, mw2, mb2, (float*)d_out);
}